// Round 17
// baseline (448.201 us; speedup 1.0000x reference)
//
#include <hip/hip_runtime.h>

// NetVLAD fused via bf16 MFMA — SINGLE kernel with stream-K-style finisher.
// R17 = R15 stage1 (5 barriers, 40.3 KB LDS, OOB-safe) + last-4-blocks-per-batch
// finisher protocol replacing the separate stage2 kernel (saves dispatch + gap).
//   s = x·W, a = softmax_k(s), v = a^T x + (sum a)·C
// x: [64,784,512] f32, W/C: [512,32] f32, out: [64, 512*32] f32
#define NB 64
#define HW 784
#define DD 512
#define KK 32
#define BPB 28            // blocks per batch (28 px each: 28*28 = 784 = HW)
#define PPB 28            // valid pixels per block
#define SLOTS 32          // logical px slots in MFMA (28 valid + 4 masked a=0)

typedef __attribute__((ext_vector_type(8))) short bf16x8;   // 8 bf16 (4 VGPR)
typedef __attribute__((ext_vector_type(4))) float f32x4;    // MFMA 16x16 acc
typedef __attribute__((ext_vector_type(4))) unsigned short u16x4;

// ws: bf16 partials [NB*BPB][4 waves][16 frags][64 lanes] u16x4 (8 B each),
//     fp32 asums [NB*BPB][KK], then int counters [NB]
#define NBLK (NB * BPB)
#define PART_BYTES ((size_t)NBLK * 4 * 16 * 64 * 8)
#define ASUM_BYTES ((size_t)NBLK * KK * 4)
#define CNT_OFF    (PART_BYTES + ASUM_BYTES)
#define WS_NEED    (CNT_OFF + (size_t)NB * 4)

__device__ __forceinline__ unsigned short f2bf(float f) {
    unsigned u = __float_as_uint(f);
    u += 0x7fffu + ((u >> 16) & 1u);      // round-to-nearest-even
    return (unsigned short)(u >> 16);
}
__device__ __forceinline__ float bf2f(unsigned short u) {
    return __uint_as_float((unsigned)u << 16);
}
// packed f32x2 -> bf16x2, one instruction (lo = a, hi = b; T12 recipe)
__device__ __forceinline__ unsigned cvtpk(float a, float b) {
    unsigned r;
    asm("v_cvt_pk_bf16_f32 %0, %1, %2" : "=v"(r) : "v"(a), "v"(b));
    return r;
}

template <bool USE_WS>
__global__ __launch_bounds__(256) void netvlad_stage1(
    const float* __restrict__ x, const float* __restrict__ Wg,
    const float* __restrict__ Cg, float* __restrict__ out,
    void* __restrict__ ws)
{
    // LDS 40,256 B; xs doubles as the finisher's fp32 transpose buffer (16.9KB)
    __shared__ __align__(16) unsigned short xs[28 * 520];      // 29,120 B bf16
    __shared__ unsigned short spart[4][SLOTS][33];             // 8,448 B bf16 partials
    __shared__ __align__(16) unsigned short aTe[KK * 40];      // a^T [k][px] 2,560 B
    __shared__ float asumF[KK];
    __shared__ int finJsl;

    const int tid = threadIdx.x;
    const int l   = tid & 63, w = tid >> 6;      // lane, wave 0..3 (= d-slice 128w)
    const int l15 = l & 15,  lq = l >> 4;        // frag row/col, quarter
    const int k   = tid & 31, pg = tid >> 5;     // softmax mapping: pg 0..7
    const int bid = blockIdx.x;
    const int b   = bid / BPB;
    const int pb  = (bid % BPB) * PPB;
    const float* xb = x + (size_t)b * HW * DD;

    // Zero-init spart: phases A/C deliberately read past xs into this region
    // (rows 28-31); every reachable byte must be finite. 2112 dwords.
    {
        unsigned* sz = (unsigned*)spart;
#pragma unroll
        for (int i = 0; i < 8; ++i) sz[tid + 256*i] = 0u;
        if (tid < 2112 - 2048) sz[2048 + tid] = 0u;
    }

    // W B-frags: Wf[ks][nt] lane holds W[d = w*128+ks*32+lq*8+j][nt*16+l15]
    bf16x8 Wf[4][2];
#pragma unroll
    for (int ks = 0; ks < 4; ++ks)
#pragma unroll
        for (int nt = 0; nt < 2; ++nt)
#pragma unroll
            for (int j = 0; j < 8; ++j)
                Wf[ks][nt][j] = (short)f2bf(Wg[(w*128 + ks*32 + lq*8 + j) * KK + nt*16 + l15]);

    // phase-C acc: k = mt*16+lq*4+jj, d = w*128 + nt*16 + l15
    f32x4 acc[2][8];
#pragma unroll
    for (int mt = 0; mt < 2; ++mt)
#pragma unroll
        for (int nt = 0; nt < 8; ++nt)
#pragma unroll
            for (int jj = 0; jj < 4; ++jj) acc[mt][nt][jj] = 0.f;
    float asum_part = 0.f;

    // ---- stage: 28 px * 512 f32 -> bf16 LDS; 14 float4/thread, no clamp ----
#pragma unroll
    for (int h = 0; h < 2; ++h) {
        float4 r[7];
#pragma unroll
        for (int j = 0; j < 7; ++j) {
            const int f = tid + 256*(h*7 + j), row = f >> 7, c4 = f & 127;
            r[j] = *(const float4*)(xb + (size_t)(pb + row) * DD + c4*4);
        }
#pragma unroll
        for (int j = 0; j < 7; ++j) {
            const int f = tid + 256*(h*7 + j), row = f >> 7, c4 = f & 127;
            uint2 pk = make_uint2(cvtpk(r[j].x, r[j].y), cvtpk(r[j].z, r[j].w));
            *(uint2*)&xs[row*520 + c4*4] = pk;
        }
    }
    __syncthreads();

    // ---- phase A: s[32px][32k] partial over this wave's 128-d slice (16 MFMA) ----
    {
        f32x4 sp[2][2];
#pragma unroll
        for (int mt = 0; mt < 2; ++mt)
#pragma unroll
            for (int nt = 0; nt < 2; ++nt)
#pragma unroll
                for (int jj = 0; jj < 4; ++jj) sp[mt][nt][jj] = 0.f;
#pragma unroll
        for (int ks = 0; ks < 4; ++ks) {
            bf16x8 af[2];
#pragma unroll
            for (int mt = 0; mt < 2; ++mt)
                af[mt] = *(const bf16x8*)&xs[(mt*16 + l15)*520 + w*128 + ks*32 + lq*8];
#pragma unroll
            for (int mt = 0; mt < 2; ++mt)
#pragma unroll
                for (int nt = 0; nt < 2; ++nt)
                    sp[mt][nt] = __builtin_amdgcn_mfma_f32_16x16x32_bf16(
                        af[mt], Wf[ks][nt], sp[mt][nt], 0, 0, 0);
        }
        const bool padrow = (lq == 3);
#pragma unroll
        for (int mt = 0; mt < 2; ++mt)
#pragma unroll
            for (int nt = 0; nt < 2; ++nt)
#pragma unroll
                for (int jj = 0; jj < 4; ++jj) {
                    unsigned short v = f2bf(sp[mt][nt][jj]);
                    if (mt == 1 && padrow) v = 0;
                    spart[w][mt*16 + lq*4 + jj][nt*16 + l15] = v;
                }
    }
    __syncthreads();

    // ---- phase B: softmax over k; thread (pg,k), px = pg + 8i ----
#pragma unroll
    for (int i = 0; i < 4; ++i) {
        const int p = pg + 8*i;
        const float s = bf2f(spart[0][p][k]) + bf2f(spart[1][p][k])
                      + bf2f(spart[2][p][k]) + bf2f(spart[3][p][k]);
        const float e = __expf(s);
        float su = e;
#pragma unroll
        for (int msk = 16; msk >= 1; msk >>= 1)
            su += __shfl_xor(su, msk);
        const float a = (p < PPB) ? e * __builtin_amdgcn_rcpf(su) : 0.f;
        asum_part += a;
        aTe[k*40 + p] = f2bf(a);
    }
    __syncthreads();

    // ---- phase C: v^T[32k][128d-slice] += a^T[32k][32px] · x[32px][d] (16 MFMA) ----
    {
        bf16x8 afr[2];
#pragma unroll
        for (int mt = 0; mt < 2; ++mt)
            afr[mt] = *(const bf16x8*)&aTe[(mt*16 + l15)*40 + lq*8];
#pragma unroll
        for (int nt = 0; nt < 8; ++nt) {
            const int d = w*128 + nt*16 + l15;
            bf16x8 bfr;
#pragma unroll
            for (int j = 0; j < 8; ++j) {                  // column read of x, j rotated
                const int jj = (j + 2*lq) & 7;             // per-quarter bank stagger
                bfr[jj] = (short)xs[(lq*8 + jj)*520 + d];
            }
#pragma unroll
            for (int mt = 0; mt < 2; ++mt)
                acc[mt][nt] = __builtin_amdgcn_mfma_f32_16x16x32_bf16(
                    afr[mt], bfr, acc[mt][nt], 0, 0, 0);
        }
    }
    __syncthreads();

    // ---- block asum[k] reduce (ared aliases aTe: dead after phase C) ----
    float* ared = (float*)aTe;     // [8][32]
    ared[pg*KK + k] = asum_part;
    __syncthreads();
    float* wsA = (float*)((char*)ws + PART_BYTES);
    if (tid < KK) {
        float s = 0.f;
#pragma unroll
        for (int g = 0; g < 8; ++g) s += ared[g*KK + tid];
        if (USE_WS) wsA[(size_t)bid * KK + tid] = s;
        else        asumF[tid] = s;
    }

    if (!USE_WS) {
        __syncthreads();
        float* ob = out + (size_t)b * (DD * KK);
#pragma unroll
        for (int mt = 0; mt < 2; ++mt)
#pragma unroll
            for (int nt = 0; nt < 8; ++nt)
#pragma unroll
                for (int jj = 0; jj < 4; ++jj) {
                    const int kk = mt*16 + lq*4 + jj;
                    const int d  = w*128 + nt*16 + l15;
                    atomicAdd(&ob[d*KK + kk], acc[mt][nt][jj] + asumF[kk] * Cg[d*KK + kk]);
                }
        return;
    }

    // ---- bf16 partial store, thread-major: coalesced 8B streaming ----
    {
        u16x4* o = (u16x4*)ws + ((size_t)bid * 4 + w) * (16 * 64);
#pragma unroll
        for (int mt = 0; mt < 2; ++mt)
#pragma unroll
            for (int nt = 0; nt < 8; ++nt) {
                uint2 pk = make_uint2(cvtpk(acc[mt][nt][0], acc[mt][nt][1]),
                                      cvtpk(acc[mt][nt][2], acc[mt][nt][3]));
                *(uint2*)&o[(mt*8 + nt)*64 + l] = pk;
            }
    }

    // ---- stream-K finisher protocol: last 4 blocks of batch b each finish
    //      one 128-d output slice (release: fence+RMW; acquire: RMW load) ----
    __threadfence();                              // partials+asum device-visible
    if (tid == 0) {
        int* cnt = (int*)((char*)ws + CNT_OFF);
        const int old = atomicAdd(&cnt[b], 1);    // device scope by default
        int jsl = old - (BPB - 4);
        if (jsl >= 0) {
            while (atomicAdd(&cnt[b], 0) < BPB)   // spin for remaining stores
                __builtin_amdgcn_s_sleep(8);
        }
        finJsl = jsl;
    }
    __syncthreads();
    const int jsl = finJsl;
    if (jsl < 0) return;
    __threadfence();                              // acquire side

    // ---- finisher (= old stage2 body for slice jsl): sum 28 partials,
    //      add asum_total*C, transpose via LDS, write canonical out ----
    float* lds2 = (float*)xs;                     // 128*33 fp32 = 16.9KB <= 29KB
    if (tid < KK) {
        float s = 0.f;
#pragma unroll
        for (int p = 0; p < BPB; ++p)
            s += wsA[(size_t)(b*BPB + p) * KK + tid];
        asumF[tid] = s;
    }

    const u16x4* wsp = (const u16x4*)ws;
    float4 v[4];
#pragma unroll
    for (int i = 0; i < 4; ++i) v[i] = make_float4(0.f, 0.f, 0.f, 0.f);
    for (int p = 0; p < BPB; ++p) {
        const size_t base = ((size_t)(b*BPB + p) * 4 + jsl) * (16 * 64);
#pragma unroll
        for (int i = 0; i < 4; ++i) {
            const u16x4 u = wsp[base + tid + 256*i];
            v[i].x += bf2f(u[0]); v[i].y += bf2f(u[1]);
            v[i].z += bf2f(u[2]); v[i].w += bf2f(u[3]);
        }
    }
#pragma unroll
    for (int i = 0; i < 4; ++i) {
        const int flat = tid + 256*i;             // fr*64 + lane
        const int fr = flat >> 6, lane = flat & 63;
        const int mt = fr >> 3, nt = fr & 7;
        const int q = lane >> 4, r15 = lane & 15;
        const int dl = nt*16 + r15;
        const int kb = mt*16 + q*4;
        lds2[dl*33 + kb + 0] = v[i].x;
        lds2[dl*33 + kb + 1] = v[i].y;
        lds2[dl*33 + kb + 2] = v[i].z;
        lds2[dl*33 + kb + 3] = v[i].w;
    }
    __syncthreads();

    float* outw = out + (size_t)b * (DD*KK) + jsl * 128 * KK;
    const float* Cw = Cg + jsl * 128 * KK;
#pragma unroll
    for (int i = 0; i < 4; ++i) {
        const int o4 = tid + 256*i;
        const int dl = o4 >> 3, kq = (o4 & 7) * 4;
        const float4 c4 = *(const float4*)&Cw[dl*KK + kq];
        float4 rr;
        rr.x = lds2[dl*33 + kq + 0] + asumF[kq + 0] * c4.x;
        rr.y = lds2[dl*33 + kq + 1] + asumF[kq + 1] * c4.y;
        rr.z = lds2[dl*33 + kq + 2] + asumF[kq + 2] * c4.z;
        rr.w = lds2[dl*33 + kq + 3] + asumF[kq + 3] * c4.w;
        ((float4*)outw)[o4] = rr;
    }
}

extern "C" void kernel_launch(void* const* d_in, const int* in_sizes, int n_in,
                              void* d_out, int out_size, void* d_ws, size_t ws_size,
                              hipStream_t stream) {
    const float* x = (const float*)d_in[0];
    const float* W = (const float*)d_in[1];
    const float* C = (const float*)d_in[2];
    float* out = (float*)d_out;

    if (ws_size >= WS_NEED) {
        // per-batch finisher counters must start at 0 every call
        hipMemsetAsync((char*)d_ws + CNT_OFF, 0, (size_t)NB * 4, stream);
        netvlad_stage1<true><<<dim3(NBLK), dim3(256), 0, stream>>>(x, W, C, out, d_ws);
    } else {
        hipMemsetAsync(out, 0, (size_t)out_size * sizeof(float), stream);
        netvlad_stage1<false><<<dim3(NBLK), dim3(256), 0, stream>>>(x, W, C, out, d_ws);
    }
}

// Round 18
// 48.705 us; speedup vs baseline: 9.2023x; 9.2023x over previous
//
#include <hip/hip_runtime.h>

// NetVLAD fused via bf16 MFMA, two-stage, single-chunk blocks (5 barriers).
// R18 = R15 verbatim (best verified: 48.5 us, absmax 0.0625). R17's fused
// stream-K finisher regressed 9x (spin+device-fence storm) and is reverted.
//   s = x·W, a = softmax_k(s), v = a^T x + (sum a)·C
// x: [64,784,512] f32, W/C: [512,32] f32, out: [64, 512*32] f32
#define NB 64
#define HW 784
#define DD 512
#define KK 32
#define BPB 28            // blocks per batch (28 px each: 28*28 = 784 = HW)
#define PPB 28            // valid pixels per block
#define SLOTS 32          // logical px slots in MFMA (28 valid + 4 masked a=0)

typedef __attribute__((ext_vector_type(8))) short bf16x8;   // 8 bf16 (4 VGPR)
typedef __attribute__((ext_vector_type(4))) float f32x4;    // MFMA 16x16 acc
typedef __attribute__((ext_vector_type(4))) unsigned short u16x4;

// ws: bf16 partials [NB*BPB][4 waves][16 frags][64 lanes] u16x4 (8 B each),
//     then fp32 asums [NB*BPB][KK]
#define NBLK (NB * BPB)
#define PART_BYTES ((size_t)NBLK * 4 * 16 * 64 * 8)
#define WS_NEED    (PART_BYTES + (size_t)NBLK * KK * 4)

__device__ __forceinline__ unsigned short f2bf(float f) {
    unsigned u = __float_as_uint(f);
    u += 0x7fffu + ((u >> 16) & 1u);      // round-to-nearest-even
    return (unsigned short)(u >> 16);
}
__device__ __forceinline__ float bf2f(unsigned short u) {
    return __uint_as_float((unsigned)u << 16);
}
// packed f32x2 -> bf16x2, one instruction (lo = a, hi = b; T12 recipe)
__device__ __forceinline__ unsigned cvtpk(float a, float b) {
    unsigned r;
    asm("v_cvt_pk_bf16_f32 %0, %1, %2" : "=v"(r) : "v"(a), "v"(b));
    return r;
}

template <bool USE_WS>
__global__ __launch_bounds__(256) void netvlad_stage1(
    const float* __restrict__ x, const float* __restrict__ Wg,
    const float* __restrict__ Cg, float* __restrict__ out,
    void* __restrict__ ws)
{
    // LDS 40,256 B -> 4 blocks/CU (4 x 40,448 = 161,792 <= 163,840)
    __shared__ __align__(16) unsigned short xs[28 * 520];      // 29,120 B bf16
    __shared__ unsigned short spart[4][SLOTS][33];             // 8,448 B bf16 partials
    __shared__ __align__(16) unsigned short aTe[KK * 40];      // a^T [k][px] 2,560 B
    __shared__ float asumF[KK];

    const int tid = threadIdx.x;
    const int l   = tid & 63, w = tid >> 6;      // lane, wave 0..3 (= d-slice 128w)
    const int l15 = l & 15,  lq = l >> 4;        // frag row/col, quarter
    const int k   = tid & 31, pg = tid >> 5;     // softmax mapping: pg 0..7
    const int bid = blockIdx.x;
    const int b   = bid / BPB;
    const int pb  = (bid % BPB) * PPB;
    const float* xb = x + (size_t)b * HW * DD;

    // Zero-init spart: phases A/C deliberately read past xs into this region
    // (rows 28-31); every reachable byte must be finite. 2112 dwords.
    {
        unsigned* sz = (unsigned*)spart;
#pragma unroll
        for (int i = 0; i < 8; ++i) sz[tid + 256*i] = 0u;
        if (tid < 2112 - 2048) sz[2048 + tid] = 0u;
    }

    // W B-frags: Wf[ks][nt] lane holds W[d = w*128+ks*32+lq*8+j][nt*16+l15]
    bf16x8 Wf[4][2];
#pragma unroll
    for (int ks = 0; ks < 4; ++ks)
#pragma unroll
        for (int nt = 0; nt < 2; ++nt)
#pragma unroll
            for (int j = 0; j < 8; ++j)
                Wf[ks][nt][j] = (short)f2bf(Wg[(w*128 + ks*32 + lq*8 + j) * KK + nt*16 + l15]);

    // phase-C acc: k = mt*16+lq*4+jj, d = w*128 + nt*16 + l15
    f32x4 acc[2][8];
#pragma unroll
    for (int mt = 0; mt < 2; ++mt)
#pragma unroll
        for (int nt = 0; nt < 8; ++nt)
#pragma unroll
            for (int jj = 0; jj < 4; ++jj) acc[mt][nt][jj] = 0.f;
    float asum_part = 0.f;

    // ---- stage: 28 px * 512 f32 -> bf16 LDS; 14 float4/thread, no clamp ----
#pragma unroll
    for (int h = 0; h < 2; ++h) {
        float4 r[7];
#pragma unroll
        for (int j = 0; j < 7; ++j) {
            const int f = tid + 256*(h*7 + j), row = f >> 7, c4 = f & 127;
            r[j] = *(const float4*)(xb + (size_t)(pb + row) * DD + c4*4);
        }
#pragma unroll
        for (int j = 0; j < 7; ++j) {
            const int f = tid + 256*(h*7 + j), row = f >> 7, c4 = f & 127;
            uint2 pk = make_uint2(cvtpk(r[j].x, r[j].y), cvtpk(r[j].z, r[j].w));
            *(uint2*)&xs[row*520 + c4*4] = pk;
        }
    }
    __syncthreads();

    // ---- phase A: s[32px][32k] partial over this wave's 128-d slice (16 MFMA)
    //      (mt=1 rows 28-31 read past xs into zero-inited spart: finite;
    //       their outputs are force-zeroed on write below) ----
    {
        f32x4 sp[2][2];
#pragma unroll
        for (int mt = 0; mt < 2; ++mt)
#pragma unroll
            for (int nt = 0; nt < 2; ++nt)
#pragma unroll
                for (int jj = 0; jj < 4; ++jj) sp[mt][nt][jj] = 0.f;
#pragma unroll
        for (int ks = 0; ks < 4; ++ks) {
            bf16x8 af[2];
#pragma unroll
            for (int mt = 0; mt < 2; ++mt)
                af[mt] = *(const bf16x8*)&xs[(mt*16 + l15)*520 + w*128 + ks*32 + lq*8];
#pragma unroll
            for (int mt = 0; mt < 2; ++mt)
#pragma unroll
                for (int nt = 0; nt < 2; ++nt)
                    sp[mt][nt] = __builtin_amdgcn_mfma_f32_16x16x32_bf16(
                        af[mt], Wf[ks][nt], sp[mt][nt], 0, 0, 0);
        }
        // bf16 partial store; rows p>=28 (mt==1 && lq==3) written as 0 (masked px)
        const bool padrow = (lq == 3);
#pragma unroll
        for (int mt = 0; mt < 2; ++mt)
#pragma unroll
            for (int nt = 0; nt < 2; ++nt)
#pragma unroll
                for (int jj = 0; jj < 4; ++jj) {
                    unsigned short v = f2bf(sp[mt][nt][jj]);
                    if (mt == 1 && padrow) v = 0;
                    spart[w][mt*16 + lq*4 + jj][nt*16 + l15] = v;
                }
    }
    __syncthreads();

    // ---- phase B: softmax over k; thread (pg,k), px = pg + 8i ----
#pragma unroll
    for (int i = 0; i < 4; ++i) {
        const int p = pg + 8*i;
        const float s = bf2f(spart[0][p][k]) + bf2f(spart[1][p][k])
                      + bf2f(spart[2][p][k]) + bf2f(spart[3][p][k]);
        const float e = __expf(s);
        float su = e;
#pragma unroll
        for (int msk = 16; msk >= 1; msk >>= 1)
            su += __shfl_xor(su, msk);
        const float a = (p < PPB) ? e * __builtin_amdgcn_rcpf(su) : 0.f;
        asum_part += a;
        aTe[k*40 + p] = f2bf(a);
    }
    __syncthreads();

    // ---- phase C: v^T[32k][128d-slice] += a^T[32k][32px] · x[32px][d] (16 MFMA)
    //      (rows 28-31 overrun into zero-inited/finite spart; a=0 there) ----
    {
        bf16x8 afr[2];
#pragma unroll
        for (int mt = 0; mt < 2; ++mt)
            afr[mt] = *(const bf16x8*)&aTe[(mt*16 + l15)*40 + lq*8];
#pragma unroll
        for (int nt = 0; nt < 8; ++nt) {
            const int d = w*128 + nt*16 + l15;
            bf16x8 bfr;
#pragma unroll
            for (int j = 0; j < 8; ++j) {                  // column read of x, j rotated
                const int jj = (j + 2*lq) & 7;             // per-quarter bank stagger
                bfr[jj] = (short)xs[(lq*8 + jj)*520 + d];
            }
#pragma unroll
            for (int mt = 0; mt < 2; ++mt)
                acc[mt][nt] = __builtin_amdgcn_mfma_f32_16x16x32_bf16(
                    afr[mt], bfr, acc[mt][nt], 0, 0, 0);
        }
    }
    __syncthreads();

    // ---- block asum[k] reduce (ared aliases aTe: dead after phase C) ----
    float* ared = (float*)aTe;     // [8][32]
    ared[pg*KK + k] = asum_part;
    __syncthreads();
    float* wsA = (float*)((char*)ws + PART_BYTES);
    if (tid < KK) {
        float s = 0.f;
#pragma unroll
        for (int g = 0; g < 8; ++g) s += ared[g*KK + tid];
        if (USE_WS) wsA[(size_t)bid * KK + tid] = s;
        else        asumF[tid] = s;
    }

    if (USE_WS) {
        // bf16 partial store, thread-major: coalesced 8B streaming (cvt_pk packed)
        u16x4* o = (u16x4*)ws + ((size_t)bid * 4 + w) * (16 * 64);
#pragma unroll
        for (int mt = 0; mt < 2; ++mt)
#pragma unroll
            for (int nt = 0; nt < 8; ++nt) {
                uint2 pk = make_uint2(cvtpk(acc[mt][nt][0], acc[mt][nt][1]),
                                      cvtpk(acc[mt][nt][2], acc[mt][nt][3]));
                *(uint2*)&o[(mt*8 + nt)*64 + l] = pk;
            }
    } else {
        __syncthreads();
        float* ob = out + (size_t)b * (DD * KK);
#pragma unroll
        for (int mt = 0; mt < 2; ++mt)
#pragma unroll
            for (int nt = 0; nt < 8; ++nt)
#pragma unroll
                for (int jj = 0; jj < 4; ++jj) {
                    const int kk = mt*16 + lq*4 + jj;
                    const int d  = w*128 + nt*16 + l15;
                    atomicAdd(&ob[d*KK + kk], acc[mt][nt][jj] + asumF[kk] * Cg[d*KK + kk]);
                }
    }
}

// Stage 2: block = (b, 128-d slice jsl): sum 28 bf16 partials, add asum*C, write
__global__ __launch_bounds__(256) void netvlad_stage2(
    const void* __restrict__ ws, const float* __restrict__ Cg,
    float* __restrict__ out)
{
    __shared__ float lds[128 * 33];    // canonical [d_local][k], padded
    __shared__ float asumT[KK];

    const int t = threadIdx.x;
    const int b = blockIdx.x >> 2;
    const int jsl = blockIdx.x & 3;    // = stage1 wave index (d-slice 128*jsl)

    const float* wsA = (const float*)((const char*)ws + PART_BYTES);
    if (t < KK) {
        float s = 0.f;
#pragma unroll
        for (int p = 0; p < BPB; ++p)
            s += wsA[(size_t)(b*BPB + p) * KK + t];
        asumT[t] = s;
    }

    const u16x4* wsp = (const u16x4*)ws;
    float4 v[4];
#pragma unroll
    for (int i = 0; i < 4; ++i) v[i] = make_float4(0.f, 0.f, 0.f, 0.f);
    for (int p = 0; p < BPB; ++p) {
        const size_t base = ((size_t)(b*BPB + p) * 4 + jsl) * (16 * 64);
#pragma unroll
        for (int i = 0; i < 4; ++i) {
            const u16x4 u = wsp[base + t + 256*i];
            v[i].x += bf2f(u[0]); v[i].y += bf2f(u[1]);
            v[i].z += bf2f(u[2]); v[i].w += bf2f(u[3]);
        }
    }
    // scatter frag layout -> canonical [d_local][k]
#pragma unroll
    for (int i = 0; i < 4; ++i) {
        const int flat = t + 256*i;               // fr*64 + lane
        const int fr = flat >> 6, lane = flat & 63;
        const int mt = fr >> 3, nt = fr & 7;
        const int q = lane >> 4, r15 = lane & 15;
        const int dl = nt*16 + r15;
        const int kb = mt*16 + q*4;
        lds[dl*33 + kb + 0] = v[i].x;
        lds[dl*33 + kb + 1] = v[i].y;
        lds[dl*33 + kb + 2] = v[i].z;
        lds[dl*33 + kb + 3] = v[i].w;
    }
    __syncthreads();

    float* outw = out + (size_t)b * (DD*KK) + jsl * 128 * KK;
    const float* Cw = Cg + jsl * 128 * KK;
#pragma unroll
    for (int i = 0; i < 4; ++i) {
        const int o4 = t + 256*i;
        const int dl = o4 >> 3, kq = (o4 & 7) * 4;
        const float4 c4 = *(const float4*)&Cw[dl*KK + kq];
        float4 rr;
        rr.x = lds[dl*33 + kq + 0] + asumT[kq + 0] * c4.x;
        rr.y = lds[dl*33 + kq + 1] + asumT[kq + 1] * c4.y;
        rr.z = lds[dl*33 + kq + 2] + asumT[kq + 2] * c4.z;
        rr.w = lds[dl*33 + kq + 3] + asumT[kq + 3] * c4.w;
        ((float4*)outw)[o4] = rr;
    }
}

extern "C" void kernel_launch(void* const* d_in, const int* in_sizes, int n_in,
                              void* d_out, int out_size, void* d_ws, size_t ws_size,
                              hipStream_t stream) {
    const float* x = (const float*)d_in[0];
    const float* W = (const float*)d_in[1];
    const float* C = (const float*)d_in[2];
    float* out = (float*)d_out;

    if (ws_size >= WS_NEED) {
        netvlad_stage1<true><<<dim3(NBLK), dim3(256), 0, stream>>>(x, W, C, out, d_ws);
        netvlad_stage2<<<dim3(NB * 4), dim3(256), 0, stream>>>(d_ws, C, out);
    } else {
        hipMemsetAsync(out, 0, (size_t)out_size * sizeof(float), stream);
        netvlad_stage1<false><<<dim3(NBLK), dim3(256), 0, stream>>>(x, W, C, out, d_ws);
    }
}

// Round 20
// 48.631 us; speedup vs baseline: 9.2164x; 1.0015x over previous
//
#include <hip/hip_runtime.h>

// NetVLAD fused via bf16 MFMA, two-stage, single-chunk blocks (5 barriers).
// R20 = R15/R18 verbatim (best verified: 48.5 us, absmax 0.0625).
// Terminal revert: tr_b16 gather (R12/R19) failed twice on addressing
// semantics (group-uniform addr reads same value per m156 — needs per-lane
// column term); fused finisher (R17) regressed 9x. Eleven structural
// variants land 48-51 us with all pipes <30% — latency-bound plateau.
//   s = x·W, a = softmax_k(s), v = a^T x + (sum a)·C
// x: [64,784,512] f32, W/C: [512,32] f32, out: [64, 512*32] f32
#define NB 64
#define HW 784
#define DD 512
#define KK 32
#define BPB 28            // blocks per batch (28 px each: 28*28 = 784 = HW)
#define PPB 28            // valid pixels per block
#define SLOTS 32          // logical px slots in MFMA (28 valid + 4 masked a=0)

typedef __attribute__((ext_vector_type(8))) short bf16x8;   // 8 bf16 (4 VGPR)
typedef __attribute__((ext_vector_type(4))) float f32x4;    // MFMA 16x16 acc
typedef __attribute__((ext_vector_type(4))) unsigned short u16x4;

// ws: bf16 partials [NB*BPB][4 waves][16 frags][64 lanes] u16x4 (8 B each),
//     then fp32 asums [NB*BPB][KK]
#define NBLK (NB * BPB)
#define PART_BYTES ((size_t)NBLK * 4 * 16 * 64 * 8)
#define WS_NEED    (PART_BYTES + (size_t)NBLK * KK * 4)

__device__ __forceinline__ unsigned short f2bf(float f) {
    unsigned u = __float_as_uint(f);
    u += 0x7fffu + ((u >> 16) & 1u);      // round-to-nearest-even
    return (unsigned short)(u >> 16);
}
__device__ __forceinline__ float bf2f(unsigned short u) {
    return __uint_as_float((unsigned)u << 16);
}
// packed f32x2 -> bf16x2, one instruction (lo = a, hi = b; T12 recipe)
__device__ __forceinline__ unsigned cvtpk(float a, float b) {
    unsigned r;
    asm("v_cvt_pk_bf16_f32 %0, %1, %2" : "=v"(r) : "v"(a), "v"(b));
    return r;
}

template <bool USE_WS>
__global__ __launch_bounds__(256) void netvlad_stage1(
    const float* __restrict__ x, const float* __restrict__ Wg,
    const float* __restrict__ Cg, float* __restrict__ out,
    void* __restrict__ ws)
{
    // LDS 40,256 B -> 4 blocks/CU (4 x 40,448 = 161,792 <= 163,840)
    __shared__ __align__(16) unsigned short xs[28 * 520];      // 29,120 B bf16
    __shared__ unsigned short spart[4][SLOTS][33];             // 8,448 B bf16 partials
    __shared__ __align__(16) unsigned short aTe[KK * 40];      // a^T [k][px] 2,560 B
    __shared__ float asumF[KK];

    const int tid = threadIdx.x;
    const int l   = tid & 63, w = tid >> 6;      // lane, wave 0..3 (= d-slice 128w)
    const int l15 = l & 15,  lq = l >> 4;        // frag row/col, quarter
    const int k   = tid & 31, pg = tid >> 5;     // softmax mapping: pg 0..7
    const int bid = blockIdx.x;
    const int b   = bid / BPB;
    const int pb  = (bid % BPB) * PPB;
    const float* xb = x + (size_t)b * HW * DD;

    // Zero-init spart: phases A/C deliberately read past xs into this region
    // (rows 28-31); every reachable byte must be finite. 2112 dwords.
    {
        unsigned* sz = (unsigned*)spart;
#pragma unroll
        for (int i = 0; i < 8; ++i) sz[tid + 256*i] = 0u;
        if (tid < 2112 - 2048) sz[2048 + tid] = 0u;
    }

    // W B-frags: Wf[ks][nt] lane holds W[d = w*128+ks*32+lq*8+j][nt*16+l15]
    bf16x8 Wf[4][2];
#pragma unroll
    for (int ks = 0; ks < 4; ++ks)
#pragma unroll
        for (int nt = 0; nt < 2; ++nt)
#pragma unroll
            for (int j = 0; j < 8; ++j)
                Wf[ks][nt][j] = (short)f2bf(Wg[(w*128 + ks*32 + lq*8 + j) * KK + nt*16 + l15]);

    // phase-C acc: k = mt*16+lq*4+jj, d = w*128 + nt*16 + l15
    f32x4 acc[2][8];
#pragma unroll
    for (int mt = 0; mt < 2; ++mt)
#pragma unroll
        for (int nt = 0; nt < 8; ++nt)
#pragma unroll
            for (int jj = 0; jj < 4; ++jj) acc[mt][nt][jj] = 0.f;
    float asum_part = 0.f;

    // ---- stage: 28 px * 512 f32 -> bf16 LDS; 14 float4/thread, no clamp ----
#pragma unroll
    for (int h = 0; h < 2; ++h) {
        float4 r[7];
#pragma unroll
        for (int j = 0; j < 7; ++j) {
            const int f = tid + 256*(h*7 + j), row = f >> 7, c4 = f & 127;
            r[j] = *(const float4*)(xb + (size_t)(pb + row) * DD + c4*4);
        }
#pragma unroll
        for (int j = 0; j < 7; ++j) {
            const int f = tid + 256*(h*7 + j), row = f >> 7, c4 = f & 127;
            uint2 pk = make_uint2(cvtpk(r[j].x, r[j].y), cvtpk(r[j].z, r[j].w));
            *(uint2*)&xs[row*520 + c4*4] = pk;
        }
    }
    __syncthreads();

    // ---- phase A: s[32px][32k] partial over this wave's 128-d slice (16 MFMA)
    //      (mt=1 rows 28-31 read past xs into zero-inited spart: finite;
    //       their outputs are force-zeroed on write below) ----
    {
        f32x4 sp[2][2];
#pragma unroll
        for (int mt = 0; mt < 2; ++mt)
#pragma unroll
            for (int nt = 0; nt < 2; ++nt)
#pragma unroll
                for (int jj = 0; jj < 4; ++jj) sp[mt][nt][jj] = 0.f;
#pragma unroll
        for (int ks = 0; ks < 4; ++ks) {
            bf16x8 af[2];
#pragma unroll
            for (int mt = 0; mt < 2; ++mt)
                af[mt] = *(const bf16x8*)&xs[(mt*16 + l15)*520 + w*128 + ks*32 + lq*8];
#pragma unroll
            for (int mt = 0; mt < 2; ++mt)
#pragma unroll
                for (int nt = 0; nt < 2; ++nt)
                    sp[mt][nt] = __builtin_amdgcn_mfma_f32_16x16x32_bf16(
                        af[mt], Wf[ks][nt], sp[mt][nt], 0, 0, 0);
        }
        // bf16 partial store; rows p>=28 (mt==1 && lq==3) written as 0 (masked px)
        const bool padrow = (lq == 3);
#pragma unroll
        for (int mt = 0; mt < 2; ++mt)
#pragma unroll
            for (int nt = 0; nt < 2; ++nt)
#pragma unroll
                for (int jj = 0; jj < 4; ++jj) {
                    unsigned short v = f2bf(sp[mt][nt][jj]);
                    if (mt == 1 && padrow) v = 0;
                    spart[w][mt*16 + lq*4 + jj][nt*16 + l15] = v;
                }
    }
    __syncthreads();

    // ---- phase B: softmax over k; thread (pg,k), px = pg + 8i ----
#pragma unroll
    for (int i = 0; i < 4; ++i) {
        const int p = pg + 8*i;
        const float s = bf2f(spart[0][p][k]) + bf2f(spart[1][p][k])
                      + bf2f(spart[2][p][k]) + bf2f(spart[3][p][k]);
        const float e = __expf(s);
        float su = e;
#pragma unroll
        for (int msk = 16; msk >= 1; msk >>= 1)
            su += __shfl_xor(su, msk);
        const float a = (p < PPB) ? e * __builtin_amdgcn_rcpf(su) : 0.f;
        asum_part += a;
        aTe[k*40 + p] = f2bf(a);
    }
    __syncthreads();

    // ---- phase C: v^T[32k][128d-slice] += a^T[32k][32px] · x[32px][d] (16 MFMA)
    //      (rows 28-31 overrun into zero-inited/finite spart; a=0 there) ----
    {
        bf16x8 afr[2];
#pragma unroll
        for (int mt = 0; mt < 2; ++mt)
            afr[mt] = *(const bf16x8*)&aTe[(mt*16 + l15)*40 + lq*8];
#pragma unroll
        for (int nt = 0; nt < 8; ++nt) {
            const int d = w*128 + nt*16 + l15;
            bf16x8 bfr;
#pragma unroll
            for (int j = 0; j < 8; ++j) {                  // column read of x, j rotated
                const int jj = (j + 2*lq) & 7;             // per-quarter bank stagger
                bfr[jj] = (short)xs[(lq*8 + jj)*520 + d];
            }
#pragma unroll
            for (int mt = 0; mt < 2; ++mt)
                acc[mt][nt] = __builtin_amdgcn_mfma_f32_16x16x32_bf16(
                    afr[mt], bfr, acc[mt][nt], 0, 0, 0);
        }
    }
    __syncthreads();

    // ---- block asum[k] reduce (ared aliases aTe: dead after phase C) ----
    float* ared = (float*)aTe;     // [8][32]
    ared[pg*KK + k] = asum_part;
    __syncthreads();
    float* wsA = (float*)((char*)ws + PART_BYTES);
    if (tid < KK) {
        float s = 0.f;
#pragma unroll
        for (int g = 0; g < 8; ++g) s += ared[g*KK + tid];
        if (USE_WS) wsA[(size_t)bid * KK + tid] = s;
        else        asumF[tid] = s;
    }

    if (USE_WS) {
        // bf16 partial store, thread-major: coalesced 8B streaming (cvt_pk packed)
        u16x4* o = (u16x4*)ws + ((size_t)bid * 4 + w) * (16 * 64);
#pragma unroll
        for (int mt = 0; mt < 2; ++mt)
#pragma unroll
            for (int nt = 0; nt < 8; ++nt) {
                uint2 pk = make_uint2(cvtpk(acc[mt][nt][0], acc[mt][nt][1]),
                                      cvtpk(acc[mt][nt][2], acc[mt][nt][3]));
                *(uint2*)&o[(mt*8 + nt)*64 + l] = pk;
            }
    } else {
        __syncthreads();
        float* ob = out + (size_t)b * (DD * KK);
#pragma unroll
        for (int mt = 0; mt < 2; ++mt)
#pragma unroll
            for (int nt = 0; nt < 8; ++nt)
#pragma unroll
                for (int jj = 0; jj < 4; ++jj) {
                    const int kk = mt*16 + lq*4 + jj;
                    const int d  = w*128 + nt*16 + l15;
                    atomicAdd(&ob[d*KK + kk], acc[mt][nt][jj] + asumF[kk] * Cg[d*KK + kk]);
                }
    }
}

// Stage 2: block = (b, 128-d slice jsl): sum 28 bf16 partials, add asum*C, write
__global__ __launch_bounds__(256) void netvlad_stage2(
    const void* __restrict__ ws, const float* __restrict__ Cg,
    float* __restrict__ out)
{
    __shared__ float lds[128 * 33];    // canonical [d_local][k], padded
    __shared__ float asumT[KK];

    const int t = threadIdx.x;
    const int b = blockIdx.x >> 2;
    const int jsl = blockIdx.x & 3;    // = stage1 wave index (d-slice 128*jsl)

    const float* wsA = (const float*)((const char*)ws + PART_BYTES);
    if (t < KK) {
        float s = 0.f;
#pragma unroll
        for (int p = 0; p < BPB; ++p)
            s += wsA[(size_t)(b*BPB + p) * KK + t];
        asumT[t] = s;
    }

    const u16x4* wsp = (const u16x4*)ws;
    float4 v[4];
#pragma unroll
    for (int i = 0; i < 4; ++i) v[i] = make_float4(0.f, 0.f, 0.f, 0.f);
    for (int p = 0; p < BPB; ++p) {
        const size_t base = ((size_t)(b*BPB + p) * 4 + jsl) * (16 * 64);
#pragma unroll
        for (int i = 0; i < 4; ++i) {
            const u16x4 u = wsp[base + t + 256*i];
            v[i].x += bf2f(u[0]); v[i].y += bf2f(u[1]);
            v[i].z += bf2f(u[2]); v[i].w += bf2f(u[3]);
        }
    }
    // scatter frag layout -> canonical [d_local][k]
#pragma unroll
    for (int i = 0; i < 4; ++i) {
        const int flat = t + 256*i;               // fr*64 + lane
        const int fr = flat >> 6, lane = flat & 63;
        const int mt = fr >> 3, nt = fr & 7;
        const int q = lane >> 4, r15 = lane & 15;
        const int dl = nt*16 + r15;
        const int kb = mt*16 + q*4;
        lds[dl*33 + kb + 0] = v[i].x;
        lds[dl*33 + kb + 1] = v[i].y;
        lds[dl*33 + kb + 2] = v[i].z;
        lds[dl*33 + kb + 3] = v[i].w;
    }
    __syncthreads();

    float* outw = out + (size_t)b * (DD*KK) + jsl * 128 * KK;
    const float* Cw = Cg + jsl * 128 * KK;
#pragma unroll
    for (int i = 0; i < 4; ++i) {
        const int o4 = t + 256*i;
        const int dl = o4 >> 3, kq = (o4 & 7) * 4;
        const float4 c4 = *(const float4*)&Cw[dl*KK + kq];
        float4 rr;
        rr.x = lds[dl*33 + kq + 0] + asumT[kq + 0] * c4.x;
        rr.y = lds[dl*33 + kq + 1] + asumT[kq + 1] * c4.y;
        rr.z = lds[dl*33 + kq + 2] + asumT[kq + 2] * c4.z;
        rr.w = lds[dl*33 + kq + 3] + asumT[kq + 3] * c4.w;
        ((float4*)outw)[o4] = rr;
    }
}

extern "C" void kernel_launch(void* const* d_in, const int* in_sizes, int n_in,
                              void* d_out, int out_size, void* d_ws, size_t ws_size,
                              hipStream_t stream) {
    const float* x = (const float*)d_in[0];
    const float* W = (const float*)d_in[1];
    const float* C = (const float*)d_in[2];
    float* out = (float*)d_out;

    if (ws_size >= WS_NEED) {
        netvlad_stage1<true><<<dim3(NBLK), dim3(256), 0, stream>>>(x, W, C, out, d_ws);
        netvlad_stage2<<<dim3(NB * 4), dim3(256), 0, stream>>>(d_ws, C, out);
    } else {
        hipMemsetAsync(out, 0, (size_t)out_size * sizeof(float), stream);
        netvlad_stage1<false><<<dim3(NBLK), dim3(256), 0, stream>>>(x, W, C, out, d_ws);
    }
}